// Round 1
// 2125.782 us; speedup vs baseline: 1.0762x; 1.0762x over previous
//
#include <hip/hip_runtime.h>
#include <hip/hip_bf16.h>
#include <cstdio>

#define N_NODES 100000
#define N_EDGES 1600000
#define D_NODE 128
#define D_EDGE 64
#define HID 128
#define HEADS 4
#define N_LAYERS 3
#define LN_EPS 1e-5f
#define NEG_SLOPE 0.2f
#define EE (N_EDGES + N_NODES)            // edges incl. self-loops
#define EW_GRID ((N_EDGES + 255) / 256)   // 6250 blocks
#define SCAN_THREADS 1024
#define SCAN_CHUNK ((N_NODES + SCAN_THREADS - 1) / SCAN_THREADS)  // 98

typedef unsigned short bfraw;
using bf16x8 = __attribute__((ext_vector_type(8))) short;
using f32x4  = __attribute__((ext_vector_type(4))) float;

__device__ __forceinline__ float b2f(bfraw u) {
    return __uint_as_float(((unsigned)u) << 16);
}
__device__ __forceinline__ bfraw f2b(float f) {
    unsigned u = __float_as_uint(f);
    unsigned r = (u + 0x7fffu + ((u >> 16) & 1u)) >> 16;
    return (bfraw)r;
}
__device__ __forceinline__ float lrelu(float v) {
    return v > 0.f ? v : NEG_SLOPE * v;
}

// ---------------------------------------------------------------------------
// prep: wem[l][d] = mean_j We[l][d][j]; bem[l] = mean(be[l])
// ---------------------------------------------------------------------------
__global__ __launch_bounds__(256) void prep_kernel(
    const float* __restrict__ We, const float* __restrict__ be,
    float* __restrict__ wem, float* __restrict__ bem) {
    int tid = threadIdx.x;
    if (tid < N_LAYERS * D_EDGE) {
        int l = tid / D_EDGE, d = tid % D_EDGE;
        const float* row = We + ((size_t)l * D_EDGE + d) * HID;
        float s = 0.f;
        for (int j = 0; j < HID; j++) s += row[j];
        wem[tid] = s * (1.0f / HID);
    } else if (tid < N_LAYERS * D_EDGE + N_LAYERS) {
        int l = tid - N_LAYERS * D_EDGE;
        const float* row = be + (size_t)l * HID;
        float s = 0.f;
        for (int j = 0; j < HID; j++) s += row[j];
        bem[l] = s * (1.0f / HID);
    }
}

// ---------------------------------------------------------------------------
// ew[l][e] = dot(edge_attr[e], wem[l]) + bem[l]; block partials (no atomics)
// ---------------------------------------------------------------------------
__global__ __launch_bounds__(256) void ew_kernel(
    const float* __restrict__ ea, const float* __restrict__ wem,
    const float* __restrict__ bem, float* __restrict__ ew,
    float* __restrict__ partial) {
    __shared__ float wsh[N_LAYERS * D_EDGE];
    __shared__ float bsh[N_LAYERS];
    __shared__ float red[4][3];
    int tid = threadIdx.x;
    if (tid < N_LAYERS * D_EDGE) wsh[tid] = wem[tid];
    if (tid < N_LAYERS) bsh[tid] = bem[tid];
    __syncthreads();
    long long e = (long long)blockIdx.x * 256 + tid;
    float d0 = 0.f, d1 = 0.f, d2 = 0.f;
    if (e < N_EDGES) {
        const float4* row = (const float4*)(ea + (size_t)e * D_EDGE);
#pragma unroll
        for (int i = 0; i < D_EDGE / 4; i++) {
            float4 v = row[i];
            int c = i * 4;
            d0 += v.x * wsh[c] + v.y * wsh[c + 1] + v.z * wsh[c + 2] + v.w * wsh[c + 3];
            d1 += v.x * wsh[64 + c] + v.y * wsh[64 + c + 1] + v.z * wsh[64 + c + 2] + v.w * wsh[64 + c + 3];
            d2 += v.x * wsh[128 + c] + v.y * wsh[128 + c + 1] + v.z * wsh[128 + c + 2] + v.w * wsh[128 + c + 3];
        }
        ew[e] = d0 + bsh[0];
        ew[(size_t)N_EDGES + e] = d1 + bsh[1];
        ew[2 * (size_t)N_EDGES + e] = d2 + bsh[2];
    }
    float s0 = d0, s1 = d1, s2 = d2;
    for (int o = 32; o; o >>= 1) {
        s0 += __shfl_xor(s0, o);
        s1 += __shfl_xor(s1, o);
        s2 += __shfl_xor(s2, o);
    }
    int wid = tid >> 6;
    if ((tid & 63) == 0) {
        red[wid][0] = s0;
        red[wid][1] = s1;
        red[wid][2] = s2;
    }
    __syncthreads();
    if (tid < 3) {
        partial[(size_t)tid * EW_GRID + blockIdx.x] =
            red[0][tid] + red[1][tid] + red[2][tid] + red[3][tid];
    }
}

__global__ __launch_bounds__(256) void ewred_kernel(
    const float* __restrict__ partial, const float* __restrict__ bem,
    float* __restrict__ ewsum) {
    __shared__ float red[4];
    int l = blockIdx.x;
    int tid = threadIdx.x;
    float s = 0.f;
    for (int i = tid; i < EW_GRID; i += 256) s += partial[(size_t)l * EW_GRID + i];
    for (int o = 32; o; o >>= 1) s += __shfl_xor(s, o);
    int wid = tid >> 6;
    if ((tid & 63) == 0) red[wid] = s;
    __syncthreads();
    if (tid == 0)
        ewsum[l] = red[0] + red[1] + red[2] + red[3] + bem[l] * (float)N_EDGES;
}

// ---------------------------------------------------------------------------
// CSR build: deg=1 (self-loop) -> histogram -> single-block scan -> scatter
// ---------------------------------------------------------------------------
__global__ __launch_bounds__(256) void deginit_kernel(int* __restrict__ deg) {
    int i = blockIdx.x * 256 + threadIdx.x;
    if (i < N_NODES) deg[i] = 1;
}

__global__ __launch_bounds__(256) void hist_kernel(
    const int* __restrict__ ei, int* __restrict__ deg) {
    int e = blockIdx.x * 256 + threadIdx.x;
    if (e < N_EDGES) atomicAdd(&deg[ei[N_EDGES + e]], 1);
}

__global__ __launch_bounds__(SCAN_THREADS) void scan_kernel(
    const int* __restrict__ deg, int* __restrict__ rowptr, int* __restrict__ woff) {
    __shared__ int part[SCAN_THREADS];
    int tid = threadIdx.x;
    int lo = tid * SCAN_CHUNK;
    int hi = lo + SCAN_CHUNK < N_NODES ? lo + SCAN_CHUNK : N_NODES;
    int s = 0;
    for (int i = lo; i < hi; i++) s += deg[i];
    part[tid] = s;
    __syncthreads();
    for (int off = 1; off < SCAN_THREADS; off <<= 1) {
        int t = (tid >= off) ? part[tid - off] : 0;
        __syncthreads();
        part[tid] += t;
        __syncthreads();
    }
    int run = (tid == 0) ? 0 : part[tid - 1];
    for (int i = lo; i < hi; i++) {
        rowptr[i] = run;
        woff[i] = run + 1;  // slot 0 reserved for self-loop
        run += deg[i];
    }
    if (tid == 0) rowptr[N_NODES] = EE;
}

__global__ __launch_bounds__(256) void scatter_kernel(
    const int* __restrict__ ei, const float* __restrict__ ew,
    int* __restrict__ woff, int* __restrict__ csr_src,
    float* __restrict__ csr_ew) {
    int e = blockIdx.x * 256 + threadIdx.x;
    if (e >= N_EDGES) return;
    int d = ei[N_EDGES + e];
    int pos = atomicAdd(&woff[d], 1);
    csr_src[pos] = ei[e];
    csr_ew[pos] = ew[e];
    csr_ew[(size_t)EE + pos] = ew[(size_t)N_EDGES + e];
    csr_ew[2 * (size_t)EE + pos] = ew[2 * (size_t)N_EDGES + e];
}

__global__ __launch_bounds__(256) void selfloop_kernel(
    const int* __restrict__ rowptr, const float* __restrict__ ewsum,
    int* __restrict__ csr_src, float* __restrict__ csr_ew) {
    int d = blockIdx.x * 256 + threadIdx.x;
    if (d >= N_NODES) return;
    int pos = rowptr[d];
    csr_src[pos] = d;
    csr_ew[pos] = ewsum[0] * (1.0f / N_EDGES);
    csr_ew[(size_t)EE + pos] = ewsum[1] * (1.0f / N_EDGES);
    csr_ew[2 * (size_t)EE + pos] = ewsum[2] * (1.0f / N_EDGES);
}

// ---------------------------------------------------------------------------
// cast fp32 -> bf16 (vectorized, 4 elems/thread)
// ---------------------------------------------------------------------------
__global__ __launch_bounds__(256) void castnf_kernel(
    const float* __restrict__ in, bfraw* __restrict__ out, int n4) {
    int i = blockIdx.x * 256 + threadIdx.x;
    if (i >= n4) return;
    float4 v = *(const float4*)(in + (size_t)i * 4);
    ushort4 u;
    u.x = f2b(v.x); u.y = f2b(v.y); u.z = f2b(v.z); u.w = f2b(v.w);
    *(ushort4*)(out + (size_t)i * 4) = u;
}

// ---------------------------------------------------------------------------
// transpose+cast weights: in [L][128][N] fp32 -> out [L][N][128] bf16
// ---------------------------------------------------------------------------
__global__ __launch_bounds__(256) void tcast_kernel(
    const float* __restrict__ in, bfraw* __restrict__ out, int lgN, int total) {
    int t = blockIdx.x * 256 + threadIdx.x;
    if (t >= total) return;
    int k = t & 127;
    int n = (t >> 7) & ((1 << lgN) - 1);
    int l = t >> (7 + lgN);
    out[t] = f2b(in[((size_t)l << (7 + lgN)) + ((size_t)k << lgN) + n]);
}

// ---------------------------------------------------------------------------
// MFMA bf16 GEMM: C[M,N] = A[M,128] @ B[128,N], Bt pre-transposed [N][128].
// ---------------------------------------------------------------------------
template <int EPI>
__global__ __launch_bounds__(256) void gemm_mfma_kernel(
    const bfraw* __restrict__ A, const bfraw* __restrict__ Bt,
    const float* __restrict__ bias, bfraw* __restrict__ outb,
    float* __restrict__ outf, int M, int N) {
    __shared__ short Alds[64 * 136];  // +8 bf16 pad: 16B-aligned rows, bank spread
    __shared__ short Blds[64 * 136];
    int tid = threadIdx.x;
    int m0 = blockIdx.y * 64;
    int n0 = blockIdx.x * 64;
    {
        int li = tid;
#pragma unroll
        for (int i = 0; i < 4; i++, li += 256) {
            int row = li >> 4, ch = li & 15;
            uint4 v = make_uint4(0u, 0u, 0u, 0u);
            if (m0 + row < M)
                v = *(const uint4*)(A + (size_t)(m0 + row) * 128 + ch * 8);
            *(uint4*)&Alds[row * 136 + ch * 8] = v;
            uint4 bv = *(const uint4*)(Bt + (size_t)(n0 + row) * 128 + ch * 8);
            *(uint4*)&Blds[row * 136 + ch * 8] = bv;
        }
    }
    __syncthreads();
    int w = tid >> 6, lane = tid & 63;
    int quad = lane >> 4, lr = lane & 15;
    bf16x8 bfr[4];
#pragma unroll
    for (int kc = 0; kc < 4; kc++)
        bfr[kc] = *(const bf16x8*)&Blds[(w * 16 + lr) * 136 + kc * 32 + quad * 8];
#pragma unroll
    for (int mt = 0; mt < 4; mt++) {
        f32x4 acc = {0.f, 0.f, 0.f, 0.f};
#pragma unroll
        for (int kc = 0; kc < 4; kc++) {
            bf16x8 afr = *(const bf16x8*)&Alds[(mt * 16 + lr) * 136 + kc * 32 + quad * 8];
            acc = __builtin_amdgcn_mfma_f32_16x16x32_bf16(afr, bfr[kc], acc, 0, 0, 0);
        }
        int col = n0 + w * 16 + lr;
#pragma unroll
        for (int r = 0; r < 4; r++) {
            int row = m0 + mt * 16 + quad * 4 + r;
            if (row >= M) continue;
            float v = acc[r];
            if (EPI == 1) {
                v += bias[col];
                v = fmaxf(v, 0.f);
                outf[(size_t)row * 128 + col] = v;
                outb[(size_t)row * 128 + col] = f2b(v);
            } else {
                outb[(size_t)row * N + col] = f2b(v);
            }
        }
    }
}

// ---------------------------------------------------------------------------
// a_s[n,hd] = dot(h[n,hd,:], att_src[hd,:]); same for a_d
// ---------------------------------------------------------------------------
__global__ __launch_bounds__(256) void att_kernel(
    const bfraw* __restrict__ h, const float* __restrict__ att_s_l,
    const float* __restrict__ att_d_l, float* __restrict__ a_s, float* __restrict__ a_d) {
    __shared__ float ss[HEADS * HID], sd[HEADS * HID];
    int tid = threadIdx.x;
    for (int i = tid; i < HEADS * HID; i += 256) {
        ss[i] = att_s_l[i];
        sd[i] = att_d_l[i];
    }
    __syncthreads();
    long long gid = (long long)blockIdx.x * 256 + tid;
    if (gid >= (long long)N_NODES * HEADS) return;
    int n = (int)(gid >> 2), hd = (int)(gid & 3);
    const uint4* hv = (const uint4*)(h + (size_t)n * (HEADS * HID) + hd * HID);
    const float* ssp = ss + hd * HID;
    const float* sdp = sd + hd * HID;
    float s = 0.f, d = 0.f;
#pragma unroll
    for (int i = 0; i < 16; i++) {
        uint4 u = hv[i];
        unsigned wv[4] = {u.x, u.y, u.z, u.w};
#pragma unroll
        for (int j = 0; j < 4; j++) {
            float lo = __uint_as_float(wv[j] << 16);
            float hi = __uint_as_float(wv[j] & 0xffff0000u);
            int c = i * 8 + j * 2;
            s += lo * ssp[c] + hi * ssp[c + 1];
            d += lo * sdp[c] + hi * sdp[c + 1];
        }
    }
    a_s[gid] = s;
    a_d[gid] = d;
}

// ---------------------------------------------------------------------------
// FUSED online-softmax + aggregate + bias + LayerNorm + residual + relu.
// One wave per node. Lane l: head = l>>4, owns 8 columns c8 = (l&15)*8.
// Per edge, each lane gathers its 16B slice of h[src] (wave reads full 1KB
// row, coalesced), computes the logit for its head (uniform over 16-lane
// group), and maintains online-softmax state (m, den, acc[8]) with rescale
// amortized once per 4-edge block. Eliminates the softmax kernel and the
// alpha/invd round-trips entirely.
// ---------------------------------------------------------------------------
__device__ __forceinline__ void accum8(float* acc, uint4 u, float e) {
    unsigned wv[4] = {u.x, u.y, u.z, u.w};
#pragma unroll
    for (int j = 0; j < 4; j++) {
        acc[2 * j]     += e * __uint_as_float(wv[j] << 16);
        acc[2 * j + 1] += e * __uint_as_float(wv[j] & 0xffff0000u);
    }
}

__global__ __launch_bounds__(256) void agg_sm_ln_kernel(
    const int* __restrict__ rowptr, const int* __restrict__ csr_src,
    const float* __restrict__ ewl, const float* __restrict__ a_s,
    const float* __restrict__ a_d, const bfraw* __restrict__ h,
    const float* __restrict__ bg, const float* __restrict__ gamma,
    const float* __restrict__ beta, float* __restrict__ x, bfraw* __restrict__ xb) {
    int node = blockIdx.x * 4 + (threadIdx.x >> 6);
    int lane = threadIdx.x & 63;
    if (node >= N_NODES) return;
    int head = lane >> 4;        // 0..3
    int c8 = (lane & 15) * 8;    // 8-column slice within the head
    int rs = rowptr[node], re = rowptr[node + 1];
    float ad = a_d[(size_t)node * HEADS + head];
    const bfraw* hb = h + head * HID + c8;

    float m = -1e30f, den = 0.f;
    float acc[8];
#pragma unroll
    for (int k = 0; k < 8; k++) acc[k] = 0.f;

    int i = rs;
    // unroll-by-4: 4 independent 16B gathers in flight per lane (MLP)
    for (; i + 4 <= re; i += 4) {
        int s0 = csr_src[i],     s1 = csr_src[i + 1];
        int s2 = csr_src[i + 2], s3 = csr_src[i + 3];
        float w0 = ewl[i],     w1 = ewl[i + 1];
        float w2 = ewl[i + 2], w3 = ewl[i + 3];
        uint4 u0 = *(const uint4*)(hb + (size_t)s0 * (HEADS * HID));
        uint4 u1 = *(const uint4*)(hb + (size_t)s1 * (HEADS * HID));
        uint4 u2 = *(const uint4*)(hb + (size_t)s2 * (HEADS * HID));
        uint4 u3 = *(const uint4*)(hb + (size_t)s3 * (HEADS * HID));
        float as0 = a_s[(size_t)s0 * HEADS + head];
        float as1 = a_s[(size_t)s1 * HEADS + head];
        float as2 = a_s[(size_t)s2 * HEADS + head];
        float as3 = a_s[(size_t)s3 * HEADS + head];
        float l0 = lrelu(as0 + ad + w0);
        float l1 = lrelu(as1 + ad + w1);
        float l2 = lrelu(as2 + ad + w2);
        float l3 = lrelu(as3 + ad + w3);
        float mx = fmaxf(fmaxf(l0, l1), fmaxf(l2, l3));
        if (mx > m) {            // rescale amortized once per 4 edges
            float c = __expf(m - mx);
            den *= c;
#pragma unroll
            for (int k = 0; k < 8; k++) acc[k] *= c;
            m = mx;
        }
        float e0 = __expf(l0 - m), e1 = __expf(l1 - m);
        float e2 = __expf(l2 - m), e3 = __expf(l3 - m);
        den += e0 + e1 + e2 + e3;
        accum8(acc, u0, e0);
        accum8(acc, u1, e1);
        accum8(acc, u2, e2);
        accum8(acc, u3, e3);
    }
    for (; i < re; i++) {
        int s = csr_src[i];
        float w = ewl[i];
        uint4 u = *(const uint4*)(hb + (size_t)s * (HEADS * HID));
        float as = a_s[(size_t)s * HEADS + head];
        float l0 = lrelu(as + ad + w);
        if (l0 > m) {
            float c = __expf(m - l0);
            den *= c;
#pragma unroll
            for (int k = 0; k < 8; k++) acc[k] *= c;
            m = l0;
        }
        float e = __expf(l0 - m);
        den += e;
        accum8(acc, u, e);
    }

    // normalize by per-head denom, then mean over heads (xor 16 and 32)
    float iv = 1.f / den;
    float y[8];
    float sum = 0.f;
#pragma unroll
    for (int k = 0; k < 8; k++) {
        float v = acc[k] * iv;
        v += __shfl_xor(v, 16);
        v += __shfl_xor(v, 32);
        y[k] = 0.25f * v + bg[c8 + k];
        sum += y[k];
    }
    // LayerNorm: all 4 head-groups now hold identical y; reduce within 16 lanes
#pragma unroll
    for (int o = 8; o; o >>= 1) sum += __shfl_xor(sum, o);
    float mu = sum * (1.f / HID);
    float vs = 0.f;
#pragma unroll
    for (int k = 0; k < 8; k++) {
        float d = y[k] - mu;
        vs += d * d;
    }
#pragma unroll
    for (int o = 8; o; o >>= 1) vs += __shfl_xor(vs, o);
    float r = rsqrtf(vs * (1.f / HID) + LN_EPS);

    if (lane < 16) {  // one head-group writes: residual + relu + bf16 shadow
        float4 xv0 = *(const float4*)(x + (size_t)node * HID + c8);
        float4 xv1 = *(const float4*)(x + (size_t)node * HID + c8 + 4);
        float xv[8] = {xv0.x, xv0.y, xv0.z, xv0.w, xv1.x, xv1.y, xv1.z, xv1.w};
        float o8[8];
#pragma unroll
        for (int k = 0; k < 8; k++) {
            float o = (y[k] - mu) * r * gamma[c8 + k] + beta[c8 + k];
            o8[k] = fmaxf(xv[k] + o, 0.f);
        }
        *(float4*)(x + (size_t)node * HID + c8) = make_float4(o8[0], o8[1], o8[2], o8[3]);
        *(float4*)(x + (size_t)node * HID + c8 + 4) = make_float4(o8[4], o8[5], o8[6], o8[7]);
        uint4 ub;
        ub.x = (unsigned)f2b(o8[0]) | ((unsigned)f2b(o8[1]) << 16);
        ub.y = (unsigned)f2b(o8[2]) | ((unsigned)f2b(o8[3]) << 16);
        ub.z = (unsigned)f2b(o8[4]) | ((unsigned)f2b(o8[5]) << 16);
        ub.w = (unsigned)f2b(o8[6]) | ((unsigned)f2b(o8[7]) << 16);
        *(uint4*)(xb + (size_t)node * HID + c8) = ub;
    }
}

extern "C" void kernel_launch(void* const* d_in, const int* in_sizes, int n_in,
                              void* d_out, int out_size, void* d_ws, size_t ws_size,
                              hipStream_t stream) {
    const float* nf      = (const float*)d_in[0];
    const int*   ei      = (const int*)d_in[1];
    const float* ea      = (const float*)d_in[2];
    const float* W0      = (const float*)d_in[3];
    const float* b0      = (const float*)d_in[4];
    const float* We      = (const float*)d_in[5];
    const float* be      = (const float*)d_in[6];
    const float* Wg      = (const float*)d_in[7];
    const float* att_src = (const float*)d_in[8];
    const float* att_dst = (const float*)d_in[9];
    const float* bg      = (const float*)d_in[10];
    const float* gamma   = (const float*)d_in[11];
    const float* beta    = (const float*)d_in[12];
    float* x = (float*)d_out;  // x lives in d_out throughout

    char* p = (char*)d_ws;
    auto alloc = [&](size_t bytes) -> void* {
        void* r = (void*)p;
        p += (bytes + 255) & ~(size_t)255;
        return r;
    };
    bfraw*  h       = (bfraw*)alloc((size_t)N_NODES * HEADS * HID * sizeof(bfraw));
    float4* alpha   = (float4*)alloc((size_t)EE * sizeof(float4));  // now only hosts nfb alias
    bfraw*  xb      = (bfraw*)alloc((size_t)N_NODES * HID * sizeof(bfraw));
    float*  a_s     = (float*)alloc((size_t)N_NODES * HEADS * sizeof(float));
    float*  a_d     = (float*)alloc((size_t)N_NODES * HEADS * sizeof(float));
    float*  ew      = (float*)alloc((size_t)N_LAYERS * N_EDGES * sizeof(float));
    int*    csr_src = (int*)alloc((size_t)EE * sizeof(int));
    float*  csr_ew  = (float*)alloc((size_t)N_LAYERS * EE * sizeof(float));
    int*    rowptr  = (int*)alloc((size_t)(N_NODES + 1) * sizeof(int));
    int*    deg     = (int*)alloc((size_t)N_NODES * sizeof(int));
    int*    woff    = (int*)alloc((size_t)N_NODES * sizeof(int));
    float*  wem     = (float*)alloc((size_t)N_LAYERS * D_EDGE * sizeof(float));
    float*  bem     = (float*)alloc((size_t)N_LAYERS * sizeof(float));
    float*  ewsum   = (float*)alloc((size_t)N_LAYERS * sizeof(float));
    float*  partial = (float*)alloc((size_t)N_LAYERS * EW_GRID * sizeof(float));
    bfraw*  W0bt    = (bfraw*)alloc((size_t)HID * D_NODE * sizeof(bfraw));
    bfraw*  Wgbt    = (bfraw*)alloc((size_t)N_LAYERS * HEADS * HID * HID * sizeof(bfraw));
    size_t need = (size_t)(p - (char*)d_ws);
    if (need > ws_size) {
        fprintf(stderr, "kernel_launch: workspace too small: need %zu have %zu\n", need, ws_size);
        return;
    }
    // nfb (bf16 node_features) aliases alpha: the encoder GEMM consumes nfb
    // before anything else writes there. 27.2MB >= 25.6MB.
    bfraw* nfb = (bfraw*)alpha;

    prep_kernel<<<1, 256, 0, stream>>>(We, be, wem, bem);
    ew_kernel<<<EW_GRID, 256, 0, stream>>>(ea, wem, bem, ew, partial);
    ewred_kernel<<<N_LAYERS, 256, 0, stream>>>(partial, bem, ewsum);

    // CSR build
    deginit_kernel<<<(N_NODES + 255) / 256, 256, 0, stream>>>(deg);
    hist_kernel<<<(N_EDGES + 255) / 256, 256, 0, stream>>>(ei, deg);
    scan_kernel<<<1, SCAN_THREADS, 0, stream>>>(deg, rowptr, woff);
    scatter_kernel<<<(N_EDGES + 255) / 256, 256, 0, stream>>>(ei, ew, woff, csr_src, csr_ew);
    selfloop_kernel<<<(N_NODES + 255) / 256, 256, 0, stream>>>(rowptr, ewsum, csr_src, csr_ew);

    // bf16 conversions for MFMA
    castnf_kernel<<<((N_NODES * D_NODE / 4) + 255) / 256, 256, 0, stream>>>(
        nf, nfb, N_NODES * D_NODE / 4);
    tcast_kernel<<<(HID * D_NODE + 255) / 256, 256, 0, stream>>>(
        W0, W0bt, 7, HID * D_NODE);                       // [128][128] -> [128][128]^T
    tcast_kernel<<<(N_LAYERS * HID * HEADS * HID + 255) / 256, 256, 0, stream>>>(
        Wg, Wgbt, 9, N_LAYERS * HID * HEADS * HID);       // [3][128][512] -> [3][512][128]

    // node encoder: x = relu(nf @ W0 + b0), + bf16 shadow xb
    gemm_mfma_kernel<1><<<dim3(HID / 64, (N_NODES + 63) / 64), 256, 0, stream>>>(
        nfb, W0bt, b0, xb, x, N_NODES, HID);

    for (int l = 0; l < N_LAYERS; l++) {
        gemm_mfma_kernel<0><<<dim3(HEADS * HID / 64, (N_NODES + 63) / 64), 256, 0, stream>>>(
            xb, Wgbt + (size_t)l * HEADS * HID * HID, nullptr, h, nullptr,
            N_NODES, HEADS * HID);
        att_kernel<<<((long long)N_NODES * HEADS + 255) / 256, 256, 0, stream>>>(
            h, att_src + (size_t)l * HEADS * HID, att_dst + (size_t)l * HEADS * HID, a_s, a_d);
        agg_sm_ln_kernel<<<(N_NODES + 3) / 4, 256, 0, stream>>>(
            rowptr, csr_src, csr_ew + (size_t)l * EE, a_s, a_d, h,
            bg + (size_t)l * HID, gamma + (size_t)l * HID,
            beta + (size_t)l * HID, x, xb);
    }
}

// Round 2
// 2018.144 us; speedup vs baseline: 1.1336x; 1.0533x over previous
//
#include <hip/hip_runtime.h>
#include <hip/hip_bf16.h>
#include <cstdio>

#define N_NODES 100000
#define N_EDGES 1600000
#define D_NODE 128
#define D_EDGE 64
#define HID 128
#define HEADS 4
#define N_LAYERS 3
#define LN_EPS 1e-5f
#define NEG_SLOPE 0.2f
#define EE (N_EDGES + N_NODES)            // edges incl. self-loops
#define EW_GRID ((N_EDGES + 255) / 256)   // 6250 blocks
#define SCAN_THREADS 1024
#define SCAN_CHUNK ((N_NODES + SCAN_THREADS - 1) / SCAN_THREADS)  // 98

typedef unsigned short bfraw;
using bf16x8 = __attribute__((ext_vector_type(8))) short;
using f32x4  = __attribute__((ext_vector_type(4))) float;

__device__ __forceinline__ float b2f(bfraw u) {
    return __uint_as_float(((unsigned)u) << 16);
}
__device__ __forceinline__ bfraw f2b(float f) {
    unsigned u = __float_as_uint(f);
    unsigned r = (u + 0x7fffu + ((u >> 16) & 1u)) >> 16;
    return (bfraw)r;
}
__device__ __forceinline__ float lrelu(float v) {
    return v > 0.f ? v : NEG_SLOPE * v;
}

// ---------------------------------------------------------------------------
// prep: wem[l][d] = mean_j We[l][d][j]; bem[l] = mean(be[l])
// ---------------------------------------------------------------------------
__global__ __launch_bounds__(256) void prep_kernel(
    const float* __restrict__ We, const float* __restrict__ be,
    float* __restrict__ wem, float* __restrict__ bem) {
    int tid = threadIdx.x;
    if (tid < N_LAYERS * D_EDGE) {
        int l = tid / D_EDGE, d = tid % D_EDGE;
        const float* row = We + ((size_t)l * D_EDGE + d) * HID;
        float s = 0.f;
        for (int j = 0; j < HID; j++) s += row[j];
        wem[tid] = s * (1.0f / HID);
    } else if (tid < N_LAYERS * D_EDGE + N_LAYERS) {
        int l = tid - N_LAYERS * D_EDGE;
        const float* row = be + (size_t)l * HID;
        float s = 0.f;
        for (int j = 0; j < HID; j++) s += row[j];
        bem[l] = s * (1.0f / HID);
    }
}

// ---------------------------------------------------------------------------
// CSR build: deg=1 (self-loop) -> histogram -> single-block scan
// ---------------------------------------------------------------------------
__global__ __launch_bounds__(256) void deginit_kernel(int* __restrict__ deg) {
    int i = blockIdx.x * 256 + threadIdx.x;
    if (i < N_NODES) deg[i] = 1;
}

__global__ __launch_bounds__(256) void hist_kernel(
    const int* __restrict__ ei, int* __restrict__ deg) {
    int e = blockIdx.x * 256 + threadIdx.x;
    if (e < N_EDGES) atomicAdd(&deg[ei[N_EDGES + e]], 1);
}

__global__ __launch_bounds__(SCAN_THREADS) void scan_kernel(
    const int* __restrict__ deg, int* __restrict__ rowptr, int* __restrict__ woff) {
    __shared__ int part[SCAN_THREADS];
    int tid = threadIdx.x;
    int lo = tid * SCAN_CHUNK;
    int hi = lo + SCAN_CHUNK < N_NODES ? lo + SCAN_CHUNK : N_NODES;
    int s = 0;
    for (int i = lo; i < hi; i++) s += deg[i];
    part[tid] = s;
    __syncthreads();
    for (int off = 1; off < SCAN_THREADS; off <<= 1) {
        int t = (tid >= off) ? part[tid - off] : 0;
        __syncthreads();
        part[tid] += t;
        __syncthreads();
    }
    int run = (tid == 0) ? 0 : part[tid - 1];
    for (int i = lo; i < hi; i++) {
        rowptr[i] = run;
        woff[i] = run + 1;  // slot 0 reserved for self-loop
        run += deg[i];
    }
    if (tid == 0) rowptr[N_NODES] = EE;
}

// ---------------------------------------------------------------------------
// FUSED edge-weight + scatter: per edge, compute the 3 layer edge-weights
// from edge_attr (one coalesced 256B read), then ONE random 16B store of
// {src, ew0, ew1, ew2} into the CSR slot. Also block-reduces d0..d2 into
// partials for the self-loop mean. Replaces ew_kernel + scatter_kernel
// (which did 4 random 4B stores per edge + a 19MB ew round-trip).
// ---------------------------------------------------------------------------
__global__ __launch_bounds__(256) void ewscat_kernel(
    const float* __restrict__ ea, const int* __restrict__ ei,
    const float* __restrict__ wem, const float* __restrict__ bem,
    int* __restrict__ woff, uint4* __restrict__ csrq,
    float* __restrict__ partial) {
    __shared__ float wsh[N_LAYERS * D_EDGE];
    __shared__ float bsh[N_LAYERS];
    __shared__ float red[4][3];
    int tid = threadIdx.x;
    if (tid < N_LAYERS * D_EDGE) wsh[tid] = wem[tid];
    if (tid < N_LAYERS) bsh[tid] = bem[tid];
    __syncthreads();
    long long e = (long long)blockIdx.x * 256 + tid;
    float d0 = 0.f, d1 = 0.f, d2 = 0.f;
    if (e < N_EDGES) {
        const float4* row = (const float4*)(ea + (size_t)e * D_EDGE);
#pragma unroll
        for (int i = 0; i < D_EDGE / 4; i++) {
            float4 v = row[i];
            int c = i * 4;
            d0 += v.x * wsh[c] + v.y * wsh[c + 1] + v.z * wsh[c + 2] + v.w * wsh[c + 3];
            d1 += v.x * wsh[64 + c] + v.y * wsh[64 + c + 1] + v.z * wsh[64 + c + 2] + v.w * wsh[64 + c + 3];
            d2 += v.x * wsh[128 + c] + v.y * wsh[128 + c + 1] + v.z * wsh[128 + c + 2] + v.w * wsh[128 + c + 3];
        }
        int src = ei[e];
        int dst = ei[N_EDGES + e];
        int pos = atomicAdd(&woff[dst], 1);
        uint4 q;
        q.x = (unsigned)src;
        q.y = __float_as_uint(d0 + bsh[0]);
        q.z = __float_as_uint(d1 + bsh[1]);
        q.w = __float_as_uint(d2 + bsh[2]);
        csrq[pos] = q;
    }
    float s0 = d0, s1 = d1, s2 = d2;
    for (int o = 32; o; o >>= 1) {
        s0 += __shfl_xor(s0, o);
        s1 += __shfl_xor(s1, o);
        s2 += __shfl_xor(s2, o);
    }
    int wid = tid >> 6;
    if ((tid & 63) == 0) {
        red[wid][0] = s0;
        red[wid][1] = s1;
        red[wid][2] = s2;
    }
    __syncthreads();
    if (tid < 3) {
        partial[(size_t)tid * EW_GRID + blockIdx.x] =
            red[0][tid] + red[1][tid] + red[2][tid] + red[3][tid];
    }
}

__global__ __launch_bounds__(256) void ewred_kernel(
    const float* __restrict__ partial, const float* __restrict__ bem,
    float* __restrict__ ewsum) {
    __shared__ float red[4];
    int l = blockIdx.x;
    int tid = threadIdx.x;
    float s = 0.f;
    for (int i = tid; i < EW_GRID; i += 256) s += partial[(size_t)l * EW_GRID + i];
    for (int o = 32; o; o >>= 1) s += __shfl_xor(s, o);
    int wid = tid >> 6;
    if ((tid & 63) == 0) red[wid] = s;
    __syncthreads();
    if (tid == 0)
        ewsum[l] = red[0] + red[1] + red[2] + red[3] + bem[l] * (float)N_EDGES;
}

__global__ __launch_bounds__(256) void selfloop_kernel(
    const int* __restrict__ rowptr, const float* __restrict__ ewsum,
    uint4* __restrict__ csrq) {
    int d = blockIdx.x * 256 + threadIdx.x;
    if (d >= N_NODES) return;
    int pos = rowptr[d];
    uint4 q;
    q.x = (unsigned)d;
    q.y = __float_as_uint(ewsum[0] * (1.0f / N_EDGES));
    q.z = __float_as_uint(ewsum[1] * (1.0f / N_EDGES));
    q.w = __float_as_uint(ewsum[2] * (1.0f / N_EDGES));
    csrq[pos] = q;
}

// ---------------------------------------------------------------------------
// cast fp32 -> bf16 (vectorized, 4 elems/thread)
// ---------------------------------------------------------------------------
__global__ __launch_bounds__(256) void castnf_kernel(
    const float* __restrict__ in, bfraw* __restrict__ out, int n4) {
    int i = blockIdx.x * 256 + threadIdx.x;
    if (i >= n4) return;
    float4 v = *(const float4*)(in + (size_t)i * 4);
    ushort4 u;
    u.x = f2b(v.x); u.y = f2b(v.y); u.z = f2b(v.z); u.w = f2b(v.w);
    *(ushort4*)(out + (size_t)i * 4) = u;
}

// ---------------------------------------------------------------------------
// transpose+cast weights: in [L][128][N] fp32 -> out [L][N][128] bf16
// ---------------------------------------------------------------------------
__global__ __launch_bounds__(256) void tcast_kernel(
    const float* __restrict__ in, bfraw* __restrict__ out, int lgN, int total) {
    int t = blockIdx.x * 256 + threadIdx.x;
    if (t >= total) return;
    int k = t & 127;
    int n = (t >> 7) & ((1 << lgN) - 1);
    int l = t >> (7 + lgN);
    out[t] = f2b(in[((size_t)l << (7 + lgN)) + ((size_t)k << lgN) + n]);
}

// ---------------------------------------------------------------------------
// MFMA bf16 GEMM: C[M,N] = A[M,128] @ B[128,N], Bt pre-transposed [N][128].
// ---------------------------------------------------------------------------
template <int EPI>
__global__ __launch_bounds__(256) void gemm_mfma_kernel(
    const bfraw* __restrict__ A, const bfraw* __restrict__ Bt,
    const float* __restrict__ bias, bfraw* __restrict__ outb,
    float* __restrict__ outf, int M, int N) {
    __shared__ short Alds[64 * 136];  // +8 bf16 pad: 16B-aligned rows, bank spread
    __shared__ short Blds[64 * 136];
    int tid = threadIdx.x;
    int m0 = blockIdx.y * 64;
    int n0 = blockIdx.x * 64;
    {
        int li = tid;
#pragma unroll
        for (int i = 0; i < 4; i++, li += 256) {
            int row = li >> 4, ch = li & 15;
            uint4 v = make_uint4(0u, 0u, 0u, 0u);
            if (m0 + row < M)
                v = *(const uint4*)(A + (size_t)(m0 + row) * 128 + ch * 8);
            *(uint4*)&Alds[row * 136 + ch * 8] = v;
            uint4 bv = *(const uint4*)(Bt + (size_t)(n0 + row) * 128 + ch * 8);
            *(uint4*)&Blds[row * 136 + ch * 8] = bv;
        }
    }
    __syncthreads();
    int w = tid >> 6, lane = tid & 63;
    int quad = lane >> 4, lr = lane & 15;
    bf16x8 bfr[4];
#pragma unroll
    for (int kc = 0; kc < 4; kc++)
        bfr[kc] = *(const bf16x8*)&Blds[(w * 16 + lr) * 136 + kc * 32 + quad * 8];
#pragma unroll
    for (int mt = 0; mt < 4; mt++) {
        f32x4 acc = {0.f, 0.f, 0.f, 0.f};
#pragma unroll
        for (int kc = 0; kc < 4; kc++) {
            bf16x8 afr = *(const bf16x8*)&Alds[(mt * 16 + lr) * 136 + kc * 32 + quad * 8];
            acc = __builtin_amdgcn_mfma_f32_16x16x32_bf16(afr, bfr[kc], acc, 0, 0, 0);
        }
        int col = n0 + w * 16 + lr;
#pragma unroll
        for (int r = 0; r < 4; r++) {
            int row = m0 + mt * 16 + quad * 4 + r;
            if (row >= M) continue;
            float v = acc[r];
            if (EPI == 1) {
                v += bias[col];
                v = fmaxf(v, 0.f);
                outf[(size_t)row * 128 + col] = v;
                outb[(size_t)row * 128 + col] = f2b(v);
            } else {
                outb[(size_t)row * N + col] = f2b(v);
            }
        }
    }
}

// ---------------------------------------------------------------------------
// a_s[n,hd] = dot(h[n,hd,:], att_src[hd,:]); same for a_d
// ---------------------------------------------------------------------------
__global__ __launch_bounds__(256) void att_kernel(
    const bfraw* __restrict__ h, const float* __restrict__ att_s_l,
    const float* __restrict__ att_d_l, float* __restrict__ a_s, float* __restrict__ a_d) {
    __shared__ float ss[HEADS * HID], sd[HEADS * HID];
    int tid = threadIdx.x;
    for (int i = tid; i < HEADS * HID; i += 256) {
        ss[i] = att_s_l[i];
        sd[i] = att_d_l[i];
    }
    __syncthreads();
    long long gid = (long long)blockIdx.x * 256 + tid;
    if (gid >= (long long)N_NODES * HEADS) return;
    int n = (int)(gid >> 2), hd = (int)(gid & 3);
    const uint4* hv = (const uint4*)(h + (size_t)n * (HEADS * HID) + hd * HID);
    const float* ssp = ss + hd * HID;
    const float* sdp = sd + hd * HID;
    float s = 0.f, d = 0.f;
#pragma unroll
    for (int i = 0; i < 16; i++) {
        uint4 u = hv[i];
        unsigned wv[4] = {u.x, u.y, u.z, u.w};
#pragma unroll
        for (int j = 0; j < 4; j++) {
            float lo = __uint_as_float(wv[j] << 16);
            float hi = __uint_as_float(wv[j] & 0xffff0000u);
            int c = i * 8 + j * 2;
            s += lo * ssp[c] + hi * ssp[c + 1];
            d += lo * sdp[c] + hi * sdp[c + 1];
        }
    }
    a_s[gid] = s;
    a_d[gid] = d;
}

// ---------------------------------------------------------------------------
// FUSED online-softmax + aggregate + bias + LayerNorm + residual + relu.
// One wave per node. Lane l: head = l>>4, owns 8 columns c8 = (l&15)*8.
// Unroll-by-8: 8 independent 16B h-gathers + 8 a_s gathers in flight per
// lane. csrq packs {src, ew0, ew1, ew2} -> ONE 16B uniform line per edge.
// Defer-max (THR=8): rescale only when block max exceeds running max by >8;
// P bounded by e^8, den/acc stay well within fp32 range.
// ---------------------------------------------------------------------------
__device__ __forceinline__ void accum8(float* acc, uint4 u, float e) {
    unsigned wv[4] = {u.x, u.y, u.z, u.w};
#pragma unroll
    for (int j = 0; j < 4; j++) {
        acc[2 * j]     += e * __uint_as_float(wv[j] << 16);
        acc[2 * j + 1] += e * __uint_as_float(wv[j] & 0xffff0000u);
    }
}

template <int L>
__global__ __launch_bounds__(256) void agg_sm_ln_kernel(
    const int* __restrict__ rowptr, const uint4* __restrict__ csrq,
    const float* __restrict__ a_s, const float* __restrict__ a_d,
    const bfraw* __restrict__ h, const float* __restrict__ bg,
    const float* __restrict__ gamma, const float* __restrict__ beta,
    float* __restrict__ x, bfraw* __restrict__ xb) {
    int node = blockIdx.x * 4 + (threadIdx.x >> 6);
    int lane = threadIdx.x & 63;
    if (node >= N_NODES) return;
    int head = lane >> 4;        // 0..3
    int c8 = (lane & 15) * 8;    // 8-column slice within the head
    int rs = rowptr[node], re = rowptr[node + 1];
    float ad = a_d[(size_t)node * HEADS + head];
    const bfraw* hb = h + head * HID + c8;

    float m = -1e30f, den = 0.f;
    float acc[8];
#pragma unroll
    for (int k = 0; k < 8; k++) acc[k] = 0.f;

    int i = rs;
    // unroll-by-8: deep MLP
    for (; i + 8 <= re; i += 8) {
        uint4 q[8];
#pragma unroll
        for (int k = 0; k < 8; k++) q[k] = csrq[i + k];
        uint4 u[8];
        float as[8];
#pragma unroll
        for (int k = 0; k < 8; k++) {
            int s = (int)q[k].x;
            u[k] = *(const uint4*)(hb + (size_t)s * (HEADS * HID));
            as[k] = a_s[(size_t)s * HEADS + head];
        }
        float lg[8];
#pragma unroll
        for (int k = 0; k < 8; k++) {
            float w = (L == 0) ? __uint_as_float(q[k].y)
                    : (L == 1) ? __uint_as_float(q[k].z)
                               : __uint_as_float(q[k].w);
            lg[k] = lrelu(as[k] + ad + w);
        }
        float mx = lg[0];
#pragma unroll
        for (int k = 1; k < 8; k++) mx = fmaxf(mx, lg[k]);
        if (mx > m + 8.f) {  // defer-max: rescale rarely
            float c = __expf(m - mx);
            den *= c;
#pragma unroll
            for (int k = 0; k < 8; k++) acc[k] *= c;
            m = mx;
        }
#pragma unroll
        for (int k = 0; k < 8; k++) {
            float e = __expf(lg[k] - m);
            den += e;
            accum8(acc, u[k], e);
        }
    }
    // unroll-by-4 middle
    for (; i + 4 <= re; i += 4) {
        uint4 q[4];
#pragma unroll
        for (int k = 0; k < 4; k++) q[k] = csrq[i + k];
        uint4 u[4];
        float as[4];
#pragma unroll
        for (int k = 0; k < 4; k++) {
            int s = (int)q[k].x;
            u[k] = *(const uint4*)(hb + (size_t)s * (HEADS * HID));
            as[k] = a_s[(size_t)s * HEADS + head];
        }
        float lg[4];
#pragma unroll
        for (int k = 0; k < 4; k++) {
            float w = (L == 0) ? __uint_as_float(q[k].y)
                    : (L == 1) ? __uint_as_float(q[k].z)
                               : __uint_as_float(q[k].w);
            lg[k] = lrelu(as[k] + ad + w);
        }
        float mx = fmaxf(fmaxf(lg[0], lg[1]), fmaxf(lg[2], lg[3]));
        if (mx > m + 8.f) {
            float c = __expf(m - mx);
            den *= c;
#pragma unroll
            for (int k = 0; k < 8; k++) acc[k] *= c;
            m = mx;
        }
#pragma unroll
        for (int k = 0; k < 4; k++) {
            float e = __expf(lg[k] - m);
            den += e;
            accum8(acc, u[k], e);
        }
    }
    // scalar tail
    for (; i < re; i++) {
        uint4 q = csrq[i];
        int s = (int)q.x;
        float w = (L == 0) ? __uint_as_float(q.y)
                : (L == 1) ? __uint_as_float(q.z)
                           : __uint_as_float(q.w);
        uint4 u = *(const uint4*)(hb + (size_t)s * (HEADS * HID));
        float as = a_s[(size_t)s * HEADS + head];
        float l0 = lrelu(as + ad + w);
        if (l0 > m + 8.f) {
            float c = __expf(m - l0);
            den *= c;
#pragma unroll
            for (int k = 0; k < 8; k++) acc[k] *= c;
            m = l0;
        }
        float e = __expf(l0 - m);
        den += e;
        accum8(acc, u, e);
    }

    // normalize by per-head denom, then mean over heads (xor 16 and 32)
    float iv = 1.f / den;
    float y[8];
    float sum = 0.f;
#pragma unroll
    for (int k = 0; k < 8; k++) {
        float v = acc[k] * iv;
        v += __shfl_xor(v, 16);
        v += __shfl_xor(v, 32);
        y[k] = 0.25f * v + bg[c8 + k];
        sum += y[k];
    }
    // LayerNorm: all 4 head-groups now hold identical y; reduce within 16 lanes
#pragma unroll
    for (int o = 8; o; o >>= 1) sum += __shfl_xor(sum, o);
    float mu = sum * (1.f / HID);
    float vs = 0.f;
#pragma unroll
    for (int k = 0; k < 8; k++) {
        float d = y[k] - mu;
        vs += d * d;
    }
#pragma unroll
    for (int o = 8; o; o >>= 1) vs += __shfl_xor(vs, o);
    float r = rsqrtf(vs * (1.f / HID) + LN_EPS);

    if (lane < 16) {  // one head-group writes: residual + relu + bf16 shadow
        float4 xv0 = *(const float4*)(x + (size_t)node * HID + c8);
        float4 xv1 = *(const float4*)(x + (size_t)node * HID + c8 + 4);
        float xv[8] = {xv0.x, xv0.y, xv0.z, xv0.w, xv1.x, xv1.y, xv1.z, xv1.w};
        float o8[8];
#pragma unroll
        for (int k = 0; k < 8; k++) {
            float o = (y[k] - mu) * r * gamma[c8 + k] + beta[c8 + k];
            o8[k] = fmaxf(xv[k] + o, 0.f);
        }
        *(float4*)(x + (size_t)node * HID + c8) = make_float4(o8[0], o8[1], o8[2], o8[3]);
        *(float4*)(x + (size_t)node * HID + c8 + 4) = make_float4(o8[4], o8[5], o8[6], o8[7]);
        uint4 ub;
        ub.x = (unsigned)f2b(o8[0]) | ((unsigned)f2b(o8[1]) << 16);
        ub.y = (unsigned)f2b(o8[2]) | ((unsigned)f2b(o8[3]) << 16);
        ub.z = (unsigned)f2b(o8[4]) | ((unsigned)f2b(o8[5]) << 16);
        ub.w = (unsigned)f2b(o8[6]) | ((unsigned)f2b(o8[7]) << 16);
        *(uint4*)(xb + (size_t)node * HID + c8) = ub;
    }
}

extern "C" void kernel_launch(void* const* d_in, const int* in_sizes, int n_in,
                              void* d_out, int out_size, void* d_ws, size_t ws_size,
                              hipStream_t stream) {
    const float* nf      = (const float*)d_in[0];
    const int*   ei      = (const int*)d_in[1];
    const float* ea      = (const float*)d_in[2];
    const float* W0      = (const float*)d_in[3];
    const float* b0      = (const float*)d_in[4];
    const float* We      = (const float*)d_in[5];
    const float* be      = (const float*)d_in[6];
    const float* Wg      = (const float*)d_in[7];
    const float* att_src = (const float*)d_in[8];
    const float* att_dst = (const float*)d_in[9];
    const float* bg      = (const float*)d_in[10];
    const float* gamma   = (const float*)d_in[11];
    const float* beta    = (const float*)d_in[12];
    float* x = (float*)d_out;  // x lives in d_out throughout

    char* p = (char*)d_ws;
    auto alloc = [&](size_t bytes) -> void* {
        void* r = (void*)p;
        p += (bytes + 255) & ~(size_t)255;
        return r;
    };
    bfraw*  h       = (bfraw*)alloc((size_t)N_NODES * HEADS * HID * sizeof(bfraw));
    bfraw*  nfb     = (bfraw*)alloc((size_t)N_NODES * D_NODE * sizeof(bfraw));
    bfraw*  xb      = (bfraw*)alloc((size_t)N_NODES * HID * sizeof(bfraw));
    float*  a_s     = (float*)alloc((size_t)N_NODES * HEADS * sizeof(float));
    float*  a_d     = (float*)alloc((size_t)N_NODES * HEADS * sizeof(float));
    uint4*  csrq    = (uint4*)alloc((size_t)EE * sizeof(uint4));
    int*    rowptr  = (int*)alloc((size_t)(N_NODES + 1) * sizeof(int));
    int*    deg     = (int*)alloc((size_t)N_NODES * sizeof(int));
    int*    woff    = (int*)alloc((size_t)N_NODES * sizeof(int));
    float*  wem     = (float*)alloc((size_t)N_LAYERS * D_EDGE * sizeof(float));
    float*  bem     = (float*)alloc((size_t)N_LAYERS * sizeof(float));
    float*  ewsum   = (float*)alloc((size_t)N_LAYERS * sizeof(float));
    float*  partial = (float*)alloc((size_t)N_LAYERS * EW_GRID * sizeof(float));
    bfraw*  W0bt    = (bfraw*)alloc((size_t)HID * D_NODE * sizeof(bfraw));
    bfraw*  Wgbt    = (bfraw*)alloc((size_t)N_LAYERS * HEADS * HID * HID * sizeof(bfraw));
    size_t need = (size_t)(p - (char*)d_ws);
    if (need > ws_size) {
        fprintf(stderr, "kernel_launch: workspace too small: need %zu have %zu\n", need, ws_size);
        return;
    }

    prep_kernel<<<1, 256, 0, stream>>>(We, be, wem, bem);

    // CSR build + fused edge-weight scatter
    deginit_kernel<<<(N_NODES + 255) / 256, 256, 0, stream>>>(deg);
    hist_kernel<<<(N_EDGES + 255) / 256, 256, 0, stream>>>(ei, deg);
    scan_kernel<<<1, SCAN_THREADS, 0, stream>>>(deg, rowptr, woff);
    ewscat_kernel<<<EW_GRID, 256, 0, stream>>>(ea, ei, wem, bem, woff, csrq, partial);
    ewred_kernel<<<N_LAYERS, 256, 0, stream>>>(partial, bem, ewsum);
    selfloop_kernel<<<(N_NODES + 255) / 256, 256, 0, stream>>>(rowptr, ewsum, csrq);

    // bf16 conversions for MFMA
    castnf_kernel<<<((N_NODES * D_NODE / 4) + 255) / 256, 256, 0, stream>>>(
        nf, nfb, N_NODES * D_NODE / 4);
    tcast_kernel<<<(HID * D_NODE + 255) / 256, 256, 0, stream>>>(
        W0, W0bt, 7, HID * D_NODE);                       // [128][128] -> [128][128]^T
    tcast_kernel<<<(N_LAYERS * HID * HEADS * HID + 255) / 256, 256, 0, stream>>>(
        Wg, Wgbt, 9, N_LAYERS * HID * HEADS * HID);       // [3][128][512] -> [3][512][128]

    // node encoder: x = relu(nf @ W0 + b0), + bf16 shadow xb
    gemm_mfma_kernel<1><<<dim3(HID / 64, (N_NODES + 63) / 64), 256, 0, stream>>>(
        nfb, W0bt, b0, xb, x, N_NODES, HID);

    for (int l = 0; l < N_LAYERS; l++) {
        gemm_mfma_kernel<0><<<dim3(HEADS * HID / 64, (N_NODES + 63) / 64), 256, 0, stream>>>(
            xb, Wgbt + (size_t)l * HEADS * HID * HID, nullptr, h, nullptr,
            N_NODES, HEADS * HID);
        att_kernel<<<((long long)N_NODES * HEADS + 255) / 256, 256, 0, stream>>>(
            h, att_src + (size_t)l * HEADS * HID, att_dst + (size_t)l * HEADS * HID, a_s, a_d);
        if (l == 0)
            agg_sm_ln_kernel<0><<<(N_NODES + 3) / 4, 256, 0, stream>>>(
                rowptr, csrq, a_s, a_d, h, bg + (size_t)l * HID,
                gamma + (size_t)l * HID, beta + (size_t)l * HID, x, xb);
        else if (l == 1)
            agg_sm_ln_kernel<1><<<(N_NODES + 3) / 4, 256, 0, stream>>>(
                rowptr, csrq, a_s, a_d, h, bg + (size_t)l * HID,
                gamma + (size_t)l * HID, beta + (size_t)l * HID, x, xb);
        else
            agg_sm_ln_kernel<2><<<(N_NODES + 3) / 4, 256, 0, stream>>>(
                rowptr, csrq, a_s, a_d, h, bg + (size_t)l * HID,
                gamma + (size_t)l * HID, beta + (size_t)l * HID, x, xb);
    }
}

// Round 4
// 1803.203 us; speedup vs baseline: 1.2687x; 1.1192x over previous
//
#include <hip/hip_runtime.h>
#include <hip/hip_bf16.h>
#include <cstdio>

#define N_NODES 100000
#define N_EDGES 1600000
#define D_NODE 128
#define D_EDGE 64
#define HID 128
#define HEADS 4
#define N_LAYERS 3
#define LN_EPS 1e-5f
#define NEG_SLOPE 0.2f
#define EE (N_EDGES + N_NODES)            // edges incl. self-loops
#define EW_GRID ((N_EDGES + 255) / 256)   // 6250 blocks
#define SCAN_THREADS 1024
#define SCAN_CHUNK ((N_NODES + SCAN_THREADS - 1) / SCAN_THREADS)  // 98

typedef unsigned short bfraw;
using bf16x8 = __attribute__((ext_vector_type(8))) short;
using f32x4  = __attribute__((ext_vector_type(4))) float;

__device__ __forceinline__ float b2f(bfraw u) {
    return __uint_as_float(((unsigned)u) << 16);
}
__device__ __forceinline__ bfraw f2b(float f) {
    unsigned u = __float_as_uint(f);
    unsigned r = (u + 0x7fffu + ((u >> 16) & 1u)) >> 16;
    return (bfraw)r;
}
__device__ __forceinline__ float lrelu(float v) {
    return v > 0.f ? v : NEG_SLOPE * v;
}

// ---------------------------------------------------------------------------
// prep: wem[l][d] = mean_j We[l][d][j]; bem[l] = mean(be[l])
// ---------------------------------------------------------------------------
__global__ __launch_bounds__(256) void prep_kernel(
    const float* __restrict__ We, const float* __restrict__ be,
    float* __restrict__ wem, float* __restrict__ bem) {
    int tid = threadIdx.x;
    if (tid < N_LAYERS * D_EDGE) {
        int l = tid / D_EDGE, d = tid % D_EDGE;
        const float* row = We + ((size_t)l * D_EDGE + d) * HID;
        float s = 0.f;
        for (int j = 0; j < HID; j++) s += row[j];
        wem[tid] = s * (1.0f / HID);
    } else if (tid < N_LAYERS * D_EDGE + N_LAYERS) {
        int l = tid - N_LAYERS * D_EDGE;
        const float* row = be + (size_t)l * HID;
        float s = 0.f;
        for (int j = 0; j < HID; j++) s += row[j];
        bem[l] = s * (1.0f / HID);
    }
}

// ---------------------------------------------------------------------------
// wtilde: wt[l][sd][hd][c] = sum_j Wg[l][c][hd*128+j] * att_{src,dst}[l][hd][j]
// (a_s = h.att_s == x.wt_s since h = x @ Wg is linear)
// ---------------------------------------------------------------------------
__global__ __launch_bounds__(256) void wtilde_kernel(
    const float* __restrict__ Wg, const float* __restrict__ att_src,
    const float* __restrict__ att_dst, float* __restrict__ wt) {
    int t = blockIdx.x * 256 + threadIdx.x;
    if (t >= N_LAYERS * 2 * HEADS * HID) return;
    int l = t / (2 * HEADS * HID);
    int r = t % (2 * HEADS * HID);
    int sd = r >> 9;           // 0 = src, 1 = dst
    int hd = (r >> 7) & 3;
    int c = r & 127;
    const float* att = (sd ? att_dst : att_src) + ((size_t)l * HEADS + hd) * HID;
    const float* wg = Wg + (size_t)l * HID * (HEADS * HID) + (size_t)c * (HEADS * HID) + hd * HID;
    float s = 0.f;
    for (int j = 0; j < HID; j++) s += wg[j] * att[j];
    wt[t] = s;
}

// ---------------------------------------------------------------------------
// CSR build: deg=1 (self-loop) -> histogram -> single-block scan
// ---------------------------------------------------------------------------
__global__ __launch_bounds__(256) void deginit_kernel(int* __restrict__ deg) {
    int i = blockIdx.x * 256 + threadIdx.x;
    if (i < N_NODES) deg[i] = 1;
}

__global__ __launch_bounds__(256) void hist_kernel(
    const int* __restrict__ ei, int* __restrict__ deg) {
    int e = blockIdx.x * 256 + threadIdx.x;
    if (e < N_EDGES) atomicAdd(&deg[ei[N_EDGES + e]], 1);
}

__global__ __launch_bounds__(SCAN_THREADS) void scan_kernel(
    const int* __restrict__ deg, int* __restrict__ rowptr, int* __restrict__ woff) {
    __shared__ int part[SCAN_THREADS];
    int tid = threadIdx.x;
    int lo = tid * SCAN_CHUNK;
    int hi = lo + SCAN_CHUNK < N_NODES ? lo + SCAN_CHUNK : N_NODES;
    int s = 0;
    for (int i = lo; i < hi; i++) s += deg[i];
    part[tid] = s;
    __syncthreads();
    for (int off = 1; off < SCAN_THREADS; off <<= 1) {
        int t = (tid >= off) ? part[tid - off] : 0;
        __syncthreads();
        part[tid] += t;
        __syncthreads();
    }
    int run = (tid == 0) ? 0 : part[tid - 1];
    for (int i = lo; i < hi; i++) {
        rowptr[i] = run;
        woff[i] = run + 1;  // slot 0 reserved for self-loop
        run += deg[i];
    }
    if (tid == 0) rowptr[N_NODES] = EE;
}

// ---------------------------------------------------------------------------
// FUSED edge-weight + scatter: one random 16B store {src, ew0, ew1, ew2}
// ---------------------------------------------------------------------------
__global__ __launch_bounds__(256) void ewscat_kernel(
    const float* __restrict__ ea, const int* __restrict__ ei,
    const float* __restrict__ wem, const float* __restrict__ bem,
    int* __restrict__ woff, uint4* __restrict__ csrq,
    float* __restrict__ partial) {
    __shared__ float wsh[N_LAYERS * D_EDGE];
    __shared__ float bsh[N_LAYERS];
    __shared__ float red[4][3];
    int tid = threadIdx.x;
    if (tid < N_LAYERS * D_EDGE) wsh[tid] = wem[tid];
    if (tid < N_LAYERS) bsh[tid] = bem[tid];
    __syncthreads();
    long long e = (long long)blockIdx.x * 256 + tid;
    float d0 = 0.f, d1 = 0.f, d2 = 0.f;
    if (e < N_EDGES) {
        const float4* row = (const float4*)(ea + (size_t)e * D_EDGE);
#pragma unroll
        for (int i = 0; i < D_EDGE / 4; i++) {
            float4 v = row[i];
            int c = i * 4;
            d0 += v.x * wsh[c] + v.y * wsh[c + 1] + v.z * wsh[c + 2] + v.w * wsh[c + 3];
            d1 += v.x * wsh[64 + c] + v.y * wsh[64 + c + 1] + v.z * wsh[64 + c + 2] + v.w * wsh[64 + c + 3];
            d2 += v.x * wsh[128 + c] + v.y * wsh[128 + c + 1] + v.z * wsh[128 + c + 2] + v.w * wsh[128 + c + 3];
        }
        int src = ei[e];
        int dst = ei[N_EDGES + e];
        int pos = atomicAdd(&woff[dst], 1);
        uint4 q;
        q.x = (unsigned)src;
        q.y = __float_as_uint(d0 + bsh[0]);
        q.z = __float_as_uint(d1 + bsh[1]);
        q.w = __float_as_uint(d2 + bsh[2]);
        csrq[pos] = q;
    }
    float s0 = d0, s1 = d1, s2 = d2;
    for (int o = 32; o; o >>= 1) {
        s0 += __shfl_xor(s0, o);
        s1 += __shfl_xor(s1, o);
        s2 += __shfl_xor(s2, o);
    }
    int wid = tid >> 6;
    if ((tid & 63) == 0) {
        red[wid][0] = s0;
        red[wid][1] = s1;
        red[wid][2] = s2;
    }
    __syncthreads();
    if (tid < 3) {
        partial[(size_t)tid * EW_GRID + blockIdx.x] =
            red[0][tid] + red[1][tid] + red[2][tid] + red[3][tid];
    }
}

__global__ __launch_bounds__(256) void ewred_kernel(
    const float* __restrict__ partial, const float* __restrict__ bem,
    float* __restrict__ ewsum) {
    __shared__ float red[4];
    int l = blockIdx.x;
    int tid = threadIdx.x;
    float s = 0.f;
    for (int i = tid; i < EW_GRID; i += 256) s += partial[(size_t)l * EW_GRID + i];
    for (int o = 32; o; o >>= 1) s += __shfl_xor(s, o);
    int wid = tid >> 6;
    if ((tid & 63) == 0) red[wid] = s;
    __syncthreads();
    if (tid == 0)
        ewsum[l] = red[0] + red[1] + red[2] + red[3] + bem[l] * (float)N_EDGES;
}

__global__ __launch_bounds__(256) void selfloop_kernel(
    const int* __restrict__ rowptr, const float* __restrict__ ewsum,
    uint4* __restrict__ csrq) {
    int d = blockIdx.x * 256 + threadIdx.x;
    if (d >= N_NODES) return;
    int pos = rowptr[d];
    uint4 q;
    q.x = (unsigned)d;
    q.y = __float_as_uint(ewsum[0] * (1.0f / N_EDGES));
    q.z = __float_as_uint(ewsum[1] * (1.0f / N_EDGES));
    q.w = __float_as_uint(ewsum[2] * (1.0f / N_EDGES));
    csrq[pos] = q;
}

// ---------------------------------------------------------------------------
// cast fp32 -> bf16 (vectorized, 4 elems/thread)
// ---------------------------------------------------------------------------
__global__ __launch_bounds__(256) void castnf_kernel(
    const float* __restrict__ in, bfraw* __restrict__ out, int n4) {
    int i = blockIdx.x * 256 + threadIdx.x;
    if (i >= n4) return;
    float4 v = *(const float4*)(in + (size_t)i * 4);
    ushort4 u;
    u.x = f2b(v.x); u.y = f2b(v.y); u.z = f2b(v.z); u.w = f2b(v.w);
    *(ushort4*)(out + (size_t)i * 4) = u;
}

// ---------------------------------------------------------------------------
// transpose+cast W0: in [128][128] fp32 -> out [128][128]^T bf16
// ---------------------------------------------------------------------------
__global__ __launch_bounds__(256) void tcast_kernel(
    const float* __restrict__ in, bfraw* __restrict__ out, int lgN, int total) {
    int t = blockIdx.x * 256 + threadIdx.x;
    if (t >= total) return;
    int k = t & 127;
    int n = (t >> 7) & ((1 << lgN) - 1);
    int l = t >> (7 + lgN);
    out[t] = f2b(in[((size_t)l << (7 + lgN)) + ((size_t)k << lgN) + n]);
}

// ---------------------------------------------------------------------------
// Bt2[l][j][hd*128+c] = Wg[l][c][hd*128+j]  (bf16), the head-block-permuted
// transpose so that y = mean_hd(aggx_hd @ Wg_hd) = A[n, hd*128+c] @ Bt2^T
// ---------------------------------------------------------------------------
__global__ __launch_bounds__(256) void tcast2_kernel(
    const float* __restrict__ Wg, bfraw* __restrict__ Bt2) {
    int t = blockIdx.x * 256 + threadIdx.x;
    if (t >= N_LAYERS * HID * HEADS * HID) return;
    int l = t >> 16;
    int rem = t & 65535;
    int j = rem >> 9;
    int k = rem & 511;
    int hd = k >> 7;
    int c = k & 127;
    Bt2[t] = f2b(Wg[(size_t)l * 65536 + (size_t)c * 512 + hd * 128 + j]);
}

// ---------------------------------------------------------------------------
// MFMA bf16 GEMM (encoder only): x = relu(nf @ W0 + b0), + bf16 shadow xb
// ---------------------------------------------------------------------------
__global__ __launch_bounds__(256) void gemm_enc_kernel(
    const bfraw* __restrict__ A, const bfraw* __restrict__ Bt,
    const float* __restrict__ bias, bfraw* __restrict__ outb,
    float* __restrict__ outf, int M) {
    __shared__ short Alds[64 * 136];
    __shared__ short Blds[64 * 136];
    int tid = threadIdx.x;
    int m0 = blockIdx.y * 64;
    int n0 = blockIdx.x * 64;
    {
        int li = tid;
#pragma unroll
        for (int i = 0; i < 4; i++, li += 256) {
            int row = li >> 4, ch = li & 15;
            uint4 v = make_uint4(0u, 0u, 0u, 0u);
            if (m0 + row < M)
                v = *(const uint4*)(A + (size_t)(m0 + row) * 128 + ch * 8);
            *(uint4*)&Alds[row * 136 + ch * 8] = v;
            uint4 bv = *(const uint4*)(Bt + (size_t)(n0 + row) * 128 + ch * 8);
            *(uint4*)&Blds[row * 136 + ch * 8] = bv;
        }
    }
    __syncthreads();
    int w = tid >> 6, lane = tid & 63;
    int quad = lane >> 4, lr = lane & 15;
    bf16x8 bfr[4];
#pragma unroll
    for (int kc = 0; kc < 4; kc++)
        bfr[kc] = *(const bf16x8*)&Blds[(w * 16 + lr) * 136 + kc * 32 + quad * 8];
#pragma unroll
    for (int mt = 0; mt < 4; mt++) {
        f32x4 acc = {0.f, 0.f, 0.f, 0.f};
#pragma unroll
        for (int kc = 0; kc < 4; kc++) {
            bf16x8 afr = *(const bf16x8*)&Alds[(mt * 16 + lr) * 136 + kc * 32 + quad * 8];
            acc = __builtin_amdgcn_mfma_f32_16x16x32_bf16(afr, bfr[kc], acc, 0, 0, 0);
        }
        int col = n0 + w * 16 + lr;
#pragma unroll
        for (int r = 0; r < 4; r++) {
            int row = m0 + mt * 16 + quad * 4 + r;
            if (row >= M) continue;
            float v = acc[r] + bias[col];
            v = fmaxf(v, 0.f);
            outf[(size_t)row * 128 + col] = v;
            outb[(size_t)row * 128 + col] = f2b(v);
        }
    }
}

// ---------------------------------------------------------------------------
// attprep: a_s[n,hd] = x[n].wt_s[hd], a_d[n,hd] = x[n].wt_d[hd]. Wave/node.
// ---------------------------------------------------------------------------
__global__ __launch_bounds__(256) void attprep_kernel(
    const float* __restrict__ x, const float* __restrict__ wtl,
    float4* __restrict__ a_s4, float4* __restrict__ a_d4) {
    __shared__ float wsm[8][128];
    int tid = threadIdx.x;
    for (int i = tid; i < 8 * 128; i += 256) wsm[i >> 7][i & 127] = wtl[i];
    __syncthreads();
    int node = blockIdx.x * 4 + (tid >> 6);
    if (node >= N_NODES) return;
    int lane = tid & 63;
    float2 xv = *(const float2*)(x + (size_t)node * HID + lane * 2);
    float p[8];
#pragma unroll
    for (int k = 0; k < 8; k++)
        p[k] = xv.x * wsm[k][lane * 2] + xv.y * wsm[k][lane * 2 + 1];
#pragma unroll
    for (int o = 32; o; o >>= 1) {
#pragma unroll
        for (int k = 0; k < 8; k++) p[k] += __shfl_xor(p[k], o);
    }
    if (lane == 0) {
        a_s4[node] = make_float4(p[0], p[1], p[2], p[3]);
        a_d4[node] = make_float4(p[4], p[5], p[6], p[7]);
    }
}

// ---------------------------------------------------------------------------
// agg: x-space online-softmax aggregation. Wave/node. 16-lane group g owns
// edge i+g of each 4-edge step (256B x-row per group = 16 lanes x 16B);
// each lane accumulates its 8 x-cols for ALL 4 heads (acc[4][8]).
// Gather table is xb (25.6MB, L2/L3-resident) instead of h (102MB).
// Cross-group softmax-state merge at the end via shfl_xor(16|32).
// Output A[n][hd*128+c] bf16 = alpha-weighted mean of x (per head).
// ---------------------------------------------------------------------------
template <int L>
__global__ __launch_bounds__(256) void agg_kernel(
    const int* __restrict__ rowptr, const uint4* __restrict__ csrq,
    const float4* __restrict__ a_s4, const float4* __restrict__ a_d4,
    const bfraw* __restrict__ xb, bfraw* __restrict__ A) {
    int node = blockIdx.x * 4 + (threadIdx.x >> 6);
    int lane = threadIdx.x & 63;
    if (node >= N_NODES) return;
    int eslot = lane >> 4;
    int c8 = (lane & 15) * 8;
    int rs = rowptr[node], re = rowptr[node + 1];
    float4 ad4 = a_d4[node];
    float m0 = -1e30f, m1 = -1e30f, m2 = -1e30f, m3 = -1e30f;
    float d0 = 0.f, d1 = 0.f, d2 = 0.f, d3 = 0.f;
    float acc[4][8];
#pragma unroll
    for (int hd = 0; hd < 4; hd++)
#pragma unroll
        for (int k = 0; k < 8; k++) acc[hd][k] = 0.f;

    for (int i = rs; i < re; i += 4) {
        int idx = i + eslot;
        bool v = idx < re;
        int ic = v ? idx : re - 1;
        uint4 q = csrq[ic];
        int s = (int)q.x;
        float w = (L == 0) ? __uint_as_float(q.y)
                : (L == 1) ? __uint_as_float(q.z)
                           : __uint_as_float(q.w);
        uint4 u = *(const uint4*)(xb + (size_t)s * HID + c8);
        float4 as4 = a_s4[s];
        float lg0 = v ? lrelu(as4.x + ad4.x + w) : -1e30f;
        float lg1 = v ? lrelu(as4.y + ad4.y + w) : -1e30f;
        float lg2 = v ? lrelu(as4.z + ad4.z + w) : -1e30f;
        float lg3 = v ? lrelu(as4.w + ad4.w + w) : -1e30f;
        if (lg0 > m0 + 8.f || lg1 > m1 + 8.f || lg2 > m2 + 8.f || lg3 > m3 + 8.f) {
            float n0 = fmaxf(m0, lg0), s0 = __expf(m0 - n0);
            float n1 = fmaxf(m1, lg1), s1 = __expf(m1 - n1);
            float n2 = fmaxf(m2, lg2), s2 = __expf(m2 - n2);
            float n3 = fmaxf(m3, lg3), s3 = __expf(m3 - n3);
            d0 *= s0; d1 *= s1; d2 *= s2; d3 *= s3;
#pragma unroll
            for (int k = 0; k < 8; k++) {
                acc[0][k] *= s0; acc[1][k] *= s1;
                acc[2][k] *= s2; acc[3][k] *= s3;
            }
            m0 = n0; m1 = n1; m2 = n2; m3 = n3;
        }
        float f[8];
        unsigned wv[4] = {u.x, u.y, u.z, u.w};
#pragma unroll
        for (int j = 0; j < 4; j++) {
            f[2 * j] = __uint_as_float(wv[j] << 16);
            f[2 * j + 1] = __uint_as_float(wv[j] & 0xffff0000u);
        }
        float e0 = __expf(lg0 - m0), e1 = __expf(lg1 - m1);
        float e2 = __expf(lg2 - m2), e3 = __expf(lg3 - m3);
        d0 += e0; d1 += e1; d2 += e2; d3 += e3;
#pragma unroll
        for (int k = 0; k < 8; k++) {
            acc[0][k] += e0 * f[k];
            acc[1][k] += e1 * f[k];
            acc[2][k] += e2 * f[k];
            acc[3][k] += e3 * f[k];
        }
    }

    // merge the 4 edge-groups: global max, rescale, sum dens & accs, normalize
    float mh[4] = {m0, m1, m2, m3};
    float dh[4] = {d0, d1, d2, d3};
#pragma unroll
    for (int hd = 0; hd < 4; hd++) {
        float mo = mh[hd];
        float mg = fmaxf(mo, __shfl_xor(mo, 16));
        mg = fmaxf(mg, __shfl_xor(mg, 32));
        float sc = __expf(mo - mg);
        float dn = dh[hd] * sc;
        dn += __shfl_xor(dn, 16);
        dn += __shfl_xor(dn, 32);
        float inv = 1.f / dn;
#pragma unroll
        for (int k = 0; k < 8; k++) {
            float a = acc[hd][k] * sc;
            a += __shfl_xor(a, 16);
            a += __shfl_xor(a, 32);
            acc[hd][k] = a * inv;
        }
    }

    if (lane < 16) {
#pragma unroll
        for (int hd = 0; hd < 4; hd++) {
            bf16x8 pk;
#pragma unroll
            for (int k = 0; k < 8; k++) pk[k] = (short)f2b(acc[hd][k]);
            *(bf16x8*)(A + (size_t)node * 512 + hd * 128 + c8) = pk;
        }
    }
}

// ---------------------------------------------------------------------------
// gemm2ln: y = 0.25 * A[N,512] @ Bt2^T + bg, then LayerNorm + residual + relu
// fused in-block (64 rows x 128 cols per block; y-tile staged in LDS).
// Writes x fp32 and xb bf16.
// ---------------------------------------------------------------------------
__global__ __launch_bounds__(256) void gemm2ln_kernel(
    const bfraw* __restrict__ A, const bfraw* __restrict__ Bt2,
    const float* __restrict__ bg, const float* __restrict__ gamma,
    const float* __restrict__ beta, float* __restrict__ x,
    bfraw* __restrict__ xb, int M) {
    __shared__ char smem[64 * 136 * 2 + 128 * 136 * 2];  // 52224 B
    short* Alds = (short*)smem;
    short* Blds = (short*)(smem + 64 * 136 * 2);
    float* yt = (float*)smem;  // overlay: 64 x 132 fp32 = 33792 B
    int tid = threadIdx.x;
    int m0 = blockIdx.x * 64;
    int w = tid >> 6, lane = tid & 63;
    int quad = lane >> 4, lr = lane & 15;
    f32x4 acc[4][2];
#pragma unroll
    for (int mt = 0; mt < 4; mt++)
#pragma unroll
        for (int si = 0; si < 2; si++) acc[mt][si] = {0.f, 0.f, 0.f, 0.f};

    for (int kk = 0; kk < 4; kk++) {
        {
            int li = tid;
#pragma unroll
            for (int it = 0; it < 4; it++, li += 256) {
                int row = li >> 4, ch = li & 15;
                uint4 v = make_uint4(0u, 0u, 0u, 0u);
                if (m0 + row < M)
                    v = *(const uint4*)(A + (size_t)(m0 + row) * 512 + kk * 128 + ch * 8);
                *(uint4*)&Alds[row * 136 + ch * 8] = v;
            }
            li = tid;
#pragma unroll
            for (int it = 0; it < 8; it++, li += 256) {
                int row = li >> 4, ch = li & 15;
                uint4 bv = *(const uint4*)(Bt2 + (size_t)row * 512 + kk * 128 + ch * 8);
                *(uint4*)&Blds[row * 136 + ch * 8] = bv;
            }
        }
        __syncthreads();
        bf16x8 bfr[2][4];
#pragma unroll
        for (int si = 0; si < 2; si++)
#pragma unroll
            for (int kc = 0; kc < 4; kc++)
                bfr[si][kc] = *(const bf16x8*)&Blds[((w + si * 4) * 16 + lr) * 136 + kc * 32 + quad * 8];
#pragma unroll
        for (int mt = 0; mt < 4; mt++) {
#pragma unroll
            for (int kc = 0; kc < 4; kc++) {
                bf16x8 afr = *(const bf16x8*)&Alds[(mt * 16 + lr) * 136 + kc * 32 + quad * 8];
                acc[mt][0] = __builtin_amdgcn_mfma_f32_16x16x32_bf16(afr, bfr[0][kc], acc[mt][0], 0, 0, 0);
                acc[mt][1] = __builtin_amdgcn_mfma_f32_16x16x32_bf16(afr, bfr[1][kc], acc[mt][1], 0, 0, 0);
            }
        }
        __syncthreads();
    }
    // stage y tile (bias + head-mean scale) into LDS
#pragma unroll
    for (int mt = 0; mt < 4; mt++)
#pragma unroll
        for (int si = 0; si < 2; si++) {
            int col = (w + si * 4) * 16 + lr;
            float b = bg[col];
#pragma unroll
            for (int r = 0; r < 4; r++) {
                int row = mt * 16 + quad * 4 + r;
                yt[row * 132 + col] = acc[mt][si][r] * 0.25f + b;
            }
        }
    __syncthreads();
    // LN + residual + relu: wave w -> rows [w*16, w*16+16), 4 lanes/row
    int rr = lane >> 2, cg = lane & 3;
    int row = w * 16 + rr;
    int gr = m0 + row;
    const float* yrow = yt + row * 132 + cg * 32;
    float s = 0.f;
#pragma unroll
    for (int j = 0; j < 32; j++) s += yrow[j];
    s += __shfl_xor(s, 1);
    s += __shfl_xor(s, 2);
    float mu = s * (1.f / 128.f);
    float vv = 0.f;
#pragma unroll
    for (int j = 0; j < 32; j++) {
        float d = yrow[j] - mu;
        vv += d * d;
    }
    vv += __shfl_xor(vv, 1);
    vv += __shfl_xor(vv, 2);
    float rsq = rsqrtf(vv * (1.f / 128.f) + LN_EPS);
    if (gr < M) {
        float* xrow = x + (size_t)gr * 128 + cg * 32;
        bfraw* xbrow = xb + (size_t)gr * 128 + cg * 32;
#pragma unroll
        for (int j4 = 0; j4 < 8; j4++) {
            float4 xv = *(const float4*)(xrow + j4 * 4);
            float o0, o1, o2, o3;
            int c = cg * 32 + j4 * 4;
            o0 = fmaxf(xv.x + (yrow[j4 * 4 + 0] - mu) * rsq * gamma[c + 0] + beta[c + 0], 0.f);
            o1 = fmaxf(xv.y + (yrow[j4 * 4 + 1] - mu) * rsq * gamma[c + 1] + beta[c + 1], 0.f);
            o2 = fmaxf(xv.z + (yrow[j4 * 4 + 2] - mu) * rsq * gamma[c + 2] + beta[c + 2], 0.f);
            o3 = fmaxf(xv.w + (yrow[j4 * 4 + 3] - mu) * rsq * gamma[c + 3] + beta[c + 3], 0.f);
            *(float4*)(xrow + j4 * 4) = make_float4(o0, o1, o2, o3);
            ushort4 ub;
            ub.x = f2b(o0); ub.y = f2b(o1); ub.z = f2b(o2); ub.w = f2b(o3);
            *(ushort4*)(xbrow + j4 * 4) = ub;
        }
    }
}

extern "C" void kernel_launch(void* const* d_in, const int* in_sizes, int n_in,
                              void* d_out, int out_size, void* d_ws, size_t ws_size,
                              hipStream_t stream) {
    const float* nf      = (const float*)d_in[0];
    const int*   ei      = (const int*)d_in[1];
    const float* ea      = (const float*)d_in[2];
    const float* W0      = (const float*)d_in[3];
    const float* b0      = (const float*)d_in[4];
    const float* We      = (const float*)d_in[5];
    const float* be      = (const float*)d_in[6];
    const float* Wg      = (const float*)d_in[7];
    const float* att_src = (const float*)d_in[8];
    const float* att_dst = (const float*)d_in[9];
    const float* bg      = (const float*)d_in[10];
    const float* gamma   = (const float*)d_in[11];
    const float* beta    = (const float*)d_in[12];
    float* x = (float*)d_out;  // x lives in d_out throughout

    char* p = (char*)d_ws;
    auto alloc = [&](size_t bytes) -> void* {
        void* r = (void*)p;
        p += (bytes + 255) & ~(size_t)255;
        return r;
    };
    bfraw*  A       = (bfraw*)alloc((size_t)N_NODES * HEADS * HID * sizeof(bfraw));  // [N,512]
    bfraw*  nfb     = (bfraw*)alloc((size_t)N_NODES * D_NODE * sizeof(bfraw));
    bfraw*  xb      = (bfraw*)alloc((size_t)N_NODES * HID * sizeof(bfraw));
    float4* a_s4    = (float4*)alloc((size_t)N_NODES * sizeof(float4));
    float4* a_d4    = (float4*)alloc((size_t)N_NODES * sizeof(float4));
    uint4*  csrq    = (uint4*)alloc((size_t)EE * sizeof(uint4));
    int*    rowptr  = (int*)alloc((size_t)(N_NODES + 1) * sizeof(int));
    int*    deg     = (int*)alloc((size_t)N_NODES * sizeof(int));
    int*    woff    = (int*)alloc((size_t)N_NODES * sizeof(int));
    float*  wem     = (float*)alloc((size_t)N_LAYERS * D_EDGE * sizeof(float));
    float*  bem     = (float*)alloc((size_t)N_LAYERS * sizeof(float));
    float*  ewsum   = (float*)alloc((size_t)N_LAYERS * sizeof(float));
    float*  partial = (float*)alloc((size_t)N_LAYERS * EW_GRID * sizeof(float));
    float*  wt      = (float*)alloc((size_t)N_LAYERS * 2 * HEADS * HID * sizeof(float));
    bfraw*  W0bt    = (bfraw*)alloc((size_t)HID * D_NODE * sizeof(bfraw));
    bfraw*  Bt2     = (bfraw*)alloc((size_t)N_LAYERS * HID * HEADS * HID * sizeof(bfraw));
    size_t need = (size_t)(p - (char*)d_ws);
    if (need > ws_size) {
        fprintf(stderr, "kernel_launch: workspace too small: need %zu have %zu\n", need, ws_size);
        return;
    }

    prep_kernel<<<1, 256, 0, stream>>>(We, be, wem, bem);
    wtilde_kernel<<<(N_LAYERS * 2 * HEADS * HID + 255) / 256, 256, 0, stream>>>(
        Wg, att_src, att_dst, wt);

    // CSR build + fused edge-weight scatter
    deginit_kernel<<<(N_NODES + 255) / 256, 256, 0, stream>>>(deg);
    hist_kernel<<<(N_EDGES + 255) / 256, 256, 0, stream>>>(ei, deg);
    scan_kernel<<<1, SCAN_THREADS, 0, stream>>>(deg, rowptr, woff);
    ewscat_kernel<<<EW_GRID, 256, 0, stream>>>(ea, ei, wem, bem, woff, csrq, partial);
    ewred_kernel<<<N_LAYERS, 256, 0, stream>>>(partial, bem, ewsum);
    selfloop_kernel<<<(N_NODES + 255) / 256, 256, 0, stream>>>(rowptr, ewsum, csrq);

    // bf16 conversions for MFMA
    castnf_kernel<<<((N_NODES * D_NODE / 4) + 255) / 256, 256, 0, stream>>>(
        nf, nfb, N_NODES * D_NODE / 4);
    tcast_kernel<<<(HID * D_NODE + 255) / 256, 256, 0, stream>>>(
        W0, W0bt, 7, HID * D_NODE);
    tcast2_kernel<<<(N_LAYERS * HID * HEADS * HID + 255) / 256, 256, 0, stream>>>(Wg, Bt2);

    // node encoder: x = relu(nf @ W0 + b0), + bf16 shadow xb
    gemm_enc_kernel<<<dim3(HID / 64, (N_NODES + 63) / 64), 256, 0, stream>>>(
        nfb, W0bt, b0, xb, x, N_NODES);

    for (int l = 0; l < N_LAYERS; l++) {
        attprep_kernel<<<(N_NODES + 3) / 4, 256, 0, stream>>>(
            x, wt + (size_t)l * 2 * HEADS * HID, a_s4, a_d4);
        if (l == 0)
            agg_kernel<0><<<(N_NODES + 3) / 4, 256, 0, stream>>>(
                rowptr, csrq, a_s4, a_d4, xb, A);
        else if (l == 1)
            agg_kernel<1><<<(N_NODES + 3) / 4, 256, 0, stream>>>(
                rowptr, csrq, a_s4, a_d4, xb, A);
        else
            agg_kernel<2><<<(N_NODES + 3) / 4, 256, 0, stream>>>(
                rowptr, csrq, a_s4, a_d4, xb, A);
        gemm2ln_kernel<<<(N_NODES + 63) / 64, 256, 0, stream>>>(
            A, Bt2 + (size_t)l * HID * HEADS * HID, bg + (size_t)l * HID,
            gamma + (size_t)l * HID, beta + (size_t)l * HID, x, xb, N_NODES);
    }
}